// Round 12
// baseline (449.706 us; speedup 1.0000x reference)
//
#include <hip/hip_runtime.h>
#include <hip/hip_bf16.h>
#include <stdint.h>

#define NND 3072
#define NB8 (NND / 8)      // adjbits row bytes = 384
#define DD 300
#define HH 4
#define F2 1200
#define TNC 40             // ccgemm LDS pad (32 + 8)
#define MREP 5             // features sub-tiles per wave (80 features)
#define PANEL (MREP * 16)
#define KC 256             // fatt3 K-chunk (LDS-shared P tile)
#define NTASK 8            // build tasks per lane per chunk (2*32*(KC/8)/256)

typedef __attribute__((ext_vector_type(8))) short short8v;
typedef __attribute__((ext_vector_type(4))) float f32x4;
typedef __hip_bfloat16 bf16;

__device__ inline float ldin(const void* p, size_t i, int isf32) {
    return isf32 ? ((const float*)p)[i]
                 : __bfloat162float(((const bf16*)p)[i]);
}

__device__ inline ushort f2bf(float x) {
    bf16 t = __float2bfloat16(x);
    return *reinterpret_cast<ushort*>(&t);
}

__device__ inline uint pack2(float lo, float hi) {
    return (uint)f2bf(lo) | ((uint)f2bf(hi) << 16);
}

// ---- dtype sniffer: flags[0]=1 iff float inputs are f32; flags[1]=1 iff adj is int32
__global__ void k_detect(const void* emb, const void* adj, int* flags) {
    if (threadIdx.x == 0 && blockIdx.x == 0) {
        const uint16_t* u = (const uint16_t*)emb;
        int plaus = 0;
        for (int i = 0; i < 128; i++) {
            int e = (u[i] >> 7) & 0xFF;
            if (e >= 112 && e <= 143) plaus++;
        }
        flags[0] = (plaus < 100) ? 1 : 0;
        const uint8_t* b = (const uint8_t*)adj;
        int nz = 0;
        for (int i = 0; i < 256; i++) if ((i & 3) != 0 && b[i]) nz++;
        flags[1] = (nz == 0) ? 1 : 0;
    }
}

// ---- pack adjacency to 1 bit per entry: adjbits[i][j/8]
__global__ void k_adjpack(const void* adj, const int* flags, uint8_t* bits) {
    int i = blockIdx.x, o = threadIdx.x;          // o = byte index 0..383 (8 j's each)
    int adjInt = flags[1];
    uint8_t b = 0;
    if (!adjInt) {
        const uint8_t* row = (const uint8_t*)adj + (size_t)i * NND + o * 8;
        uint2 v = *(const uint2*)row;
        #pragma unroll
        for (int jj = 0; jj < 4; jj++) {
            if ((v.x >> (8 * jj)) & 0xffu) b |= 1u << jj;
            if ((v.y >> (8 * jj)) & 0xffu) b |= 1u << (4 + jj);
        }
    } else {
        const int* row = (const int*)adj + (size_t)i * NND + o * 8;
        int4 u = *(const int4*)row;
        int4 v = *(const int4*)(row + 4);
        if (u.x) b |= 1;  if (u.y) b |= 2;   if (u.z) b |= 4;   if (u.w) b |= 8;
        if (v.x) b |= 16; if (v.y) b |= 32;  if (v.z) b |= 64;  if (v.w) b |= 128;
    }
    bits[(size_t)i * NB8 + o] = b;
}

// ---- T[c][r] = A[r][c], output bf16.  grid = ((C+31)/32, (R+31)/32)
__global__ void k_transpose(const void* A, size_t baseOff, bf16* T, int R, int C,
                            const int* flags, int useFlag) {
    __shared__ bf16 t[32][33];
    int isf = useFlag ? flags[0] : 0;
    int rt = blockIdx.y * 32, ct = blockIdx.x * 32;
    int tx = threadIdx.x, ty = threadIdx.y;
    for (int i = 0; i < 4; i++) {
        int r = rt + ty + 8 * i, c = ct + tx;
        if (r < R && c < C)
            t[ty + 8 * i][tx] = __float2bfloat16(ldin(A, baseOff + (size_t)r * C + c, isf));
    }
    __syncthreads();
    for (int i = 0; i < 4; i++) {
        int c = ct + ty + 8 * i, r = rt + tx;
        if (c < C && r < R) T[(size_t)c * R + r] = t[tx][ty + 8 * i];
    }
}

// ---- u1 = W @ a[:C], u2 = W @ a[C:2C]
__global__ void k_uvec(const void* W, const void* a, float* u1, float* u2, int R, int C,
                       long Wb, long ab, long ub, const int* flags) {
    int isf = flags[0];
    int h = blockIdx.y;
    int wid = threadIdx.x >> 6, lane = threadIdx.x & 63;
    int r = blockIdx.x * 4 + wid;
    if (r >= R) return;
    float s1 = 0.f, s2 = 0.f;
    for (int c = lane; c < C; c += 64) {
        float w = ldin(W, (size_t)h * Wb + (size_t)r * C + c, isf);
        s1 += w * ldin(a, (size_t)h * ab + c, isf);
        s2 += w * ldin(a, (size_t)h * ab + C + c, isf);
    }
    for (int o = 32; o; o >>= 1) { s1 += __shfl_down(s1, o); s2 += __shfl_down(s2, o); }
    if (lane == 0) { u1[(size_t)h * ub + r] = s1; u2[(size_t)h * ub + r] = s2; }
}

// ---- o1[i] = X[i,:]·u1, o2[i] = X[i,:]·u2
__global__ void k_gemv2(const void* X, const float* u1, const float* u2, float* o1, float* o2,
                        int M, int K, long ub, long ob, const int* flags, int useFlag) {
    int isf = useFlag ? flags[0] : 0;
    int h = blockIdx.y;
    const float* U1 = u1 + (size_t)h * ub;
    const float* U2 = u2 + (size_t)h * ub;
    int wid = threadIdx.x >> 6, lane = threadIdx.x & 63;
    int row = blockIdx.x * 4 + wid;
    if (row >= M) return;
    float s1 = 0.f, s2 = 0.f;
    for (int k = lane; k < K; k += 64) {
        float x = ldin(X, (size_t)row * K + k, isf);
        s1 += x * U1[k]; s2 += x * U2[k];
    }
    for (int o = 32; o; o >>= 1) { s1 += __shfl_down(s1, o); s2 += __shfl_down(s2, o); }
    if (lane == 0) { o1[(size_t)h * ob + row] = s1; o2[(size_t)h * ob + row] = s2; }
}

// ---- fused attention GEMM, LDS-shared P tile (kills panel duplication).
// Block = 4 waves x 80-feature panels (320 features). Per K-chunk (256 j):
// all 256 lanes cooperatively build P[2][32][KC] bf16 in LDS (each lane 8
// fixed (side,i,oct) tasks -> exact partition, one exp per unique pair),
// barrier, each wave consumes the whole chunk via ds_read B-fragments
// (layout = MFMA B: lane&15 -> i, lane>>4 -> j-octet), barrier. Row sums:
// per-task register partials, 32-lane shfl-reduce -> lmS[64] at the end.
__global__ __launch_bounds__(256, 2) void k_fatt3(
    const float* __restrict__ Wh1A, const float* __restrict__ Wh2A, long hs,
    const uint8_t* __restrict__ adjbits,
    const bf16* __restrict__ Xt,           // [rowsPad][NND] feature-major, zero-padded
    bf16* __restrict__ CC, long ccHeadStride, int ccStride, int F, int FBLK) {
    __shared__ __align__(16) bf16 P[2][32][KC + 8];
    __shared__ float lmS[64];
    int h = blockIdx.z;
    const float* Wh1 = Wh1A + (size_t)h * hs;
    const float* Wh2 = Wh2A + (size_t)h * hs;
    bf16* C = CC + (size_t)h * ccHeadStride;
    int tid = threadIdx.x, w = tid >> 6, lane = tid & 63;
    int ibase = blockIdx.x * 32;
    int fbase = blockIdx.y * FBLK + w * PANEL;
    // fixed per-lane build-task constants
    float w1_r[NTASK], tsum[NTASK];
    int abOff_r[NTASK];
    #pragma unroll
    for (int r = 0; r < NTASK; r++) {
        int t = tid + 256 * r;
        int i_ = (t & 1023) >> 5;
        w1_r[r] = Wh1[ibase + i_];
        abOff_r[r] = (ibase + i_) * NB8 + (t & 31);
        tsum[r] = 0.f;
    }
    int ko = (lane >> 4) * 8;
    const bf16* Abase = Xt + (size_t)(fbase + (lane & 15)) * NND + ko;
    f32x4 acc[MREP][2][2] = {};            // [m][itile][side]

    for (int k0 = 0; k0 < NND; k0 += KC) {
        // ---- build phase: each lane its 8 tasks (one j-octet, one side, one i)
        #pragma unroll
        for (int r = 0; r < NTASK; r++) {
            int t = tid + 256 * r;
            int side = t >> 10, i_ = (t & 1023) >> 5, oct = t & 31;
            uint8_t mby = adjbits[abOff_r[r] + (k0 >> 3)];
            const float* wp = Wh2 + k0 + oct * 8;
            float4 wa = *(const float4*)wp;
            float4 wb = *(const float4*)(wp + 4);
            float zs[8] = {wa.x, wa.y, wa.z, wa.w, wb.x, wb.y, wb.z, wb.w};
            float sgn = side ? -1.f : 1.f;
            ushort pu[8];
            float s = 0.f;
            #pragma unroll
            for (int jj = 0; jj < 8; jj++) {
                float z = w1_r[r] + zs[jj];
                float e = fmaxf(z, 0.3f * z);
                float v = ((mby >> jj) & 1) ? __expf(sgn * e) : 0.f;
                s += v;
                pu[jj] = f2bf(v);
            }
            tsum[r] += s;
            *(short8v*)&P[side][i_][oct * 8] = *(const short8v*)pu;
        }
        __syncthreads();
        // ---- MFMA phase: consume the full chunk
        #pragma unroll
        for (int kk = 0; kk < KC / 32; kk++) {
            short8v bp1 = *(const short8v*)&P[0][lane & 15][kk * 32 + ko];
            short8v bq1 = *(const short8v*)&P[1][lane & 15][kk * 32 + ko];
            short8v bp2 = *(const short8v*)&P[0][16 + (lane & 15)][kk * 32 + ko];
            short8v bq2 = *(const short8v*)&P[1][16 + (lane & 15)][kk * 32 + ko];
            #pragma unroll
            for (int m = 0; m < MREP; m++) {
                short8v a = *(const short8v*)(Abase + (size_t)m * 16 * NND + k0 + kk * 32);
                acc[m][0][0] = __builtin_amdgcn_mfma_f32_16x16x32_bf16(a, bp1, acc[m][0][0], 0, 0, 0);
                acc[m][0][1] = __builtin_amdgcn_mfma_f32_16x16x32_bf16(a, bq1, acc[m][0][1], 0, 0, 0);
                acc[m][1][0] = __builtin_amdgcn_mfma_f32_16x16x32_bf16(a, bp2, acc[m][1][0], 0, 0, 0);
                acc[m][1][1] = __builtin_amdgcn_mfma_f32_16x16x32_bf16(a, bq2, acc[m][1][1], 0, 0, 0);
            }
        }
        __syncthreads();
    }

    // ---- row-sum reduction: 32 consecutive lanes share each (side,i) slot
    #pragma unroll
    for (int r = 0; r < NTASK; r++) {
        float s = tsum[r];
        s += __shfl_xor(s, 1);  s += __shfl_xor(s, 2);
        s += __shfl_xor(s, 4);  s += __shfl_xor(s, 8);
        s += __shfl_xor(s, 16);
        if ((tid & 31) == 0) {
            int t = tid + 256 * r;
            lmS[t >> 5 >= 32 ? (t >> 5) : (t >> 5)] = s;   // slot = t>>5 in [0,64)
        }
    }
    __syncthreads();

    // ---- store: scale by 1/rowsum from lmS
    int li = lane & 15;
    float sp1 = lmS[li],      sn1 = lmS[32 + li];
    float sp2 = lmS[li + 16], sn2 = lmS[32 + li + 16];
    float sc1[2] = { 1.0f / sp1, -1.0f / sn1 };
    float sc2[2] = { 1.0f / sp2, -1.0f / sn2 };
    int fo = (lane >> 4) * 4;
    bf16* crow1 = C + (size_t)(ibase + li) * ccStride;
    bf16* crow2 = C + (size_t)(ibase + li + 16) * ccStride;
    #pragma unroll
    for (int m = 0; m < MREP; m++) {
        int fc = fbase + m * 16 + fo;
        if (fc >= F) continue;
        #pragma unroll
        for (int side = 0; side < 2; side++) {
            uint2 u1v, u2v;
            u1v.x = pack2(acc[m][0][side][0] * sc1[side], acc[m][0][side][1] * sc1[side]);
            u1v.y = pack2(acc[m][0][side][2] * sc1[side], acc[m][0][side][3] * sc1[side]);
            u2v.x = pack2(acc[m][1][side][0] * sc2[side], acc[m][1][side][1] * sc2[side]);
            u2v.y = pack2(acc[m][1][side][2] * sc2[side], acc[m][1][side][3] * sc2[side]);
            *(uint2*)(crow1 + side * F + fc) = u1v;
            *(uint2*)(crow2 + side * F + fc) = u2v;
        }
    }
}

// ---- Out[:,off:off+N] = epi(A @ Bt^T); M-tile 32, N-tile 64; head-batched via blockIdx.z
__global__ __launch_bounds__(256) void k_ccgemm(const bf16* __restrict__ A0, const bf16* __restrict__ Bt0,
                                                bf16* __restrict__ Out, int K, int Ncols,
                                                int outStride, int outColOff0, int mode,
                                                long aHeadStride, long btHeadStride, int outColStep) {
    __shared__ __align__(16) bf16 Alds[32 * TNC];
    __shared__ __align__(16) bf16 Blds[64 * TNC];
    int h = blockIdx.z;
    const bf16* A = A0 + (size_t)h * aHeadStride;
    const bf16* Bt = Bt0 + (size_t)h * btHeadStride;
    int outColOff = outColOff0 + h * outColStep;
    int tid = threadIdx.x, lane = tid & 63, w = tid >> 6, wr = w >> 1, wc = w & 1;
    int m0 = blockIdx.y * 32, n0 = blockIdx.x * 64;
    int smA = tid >> 3, skA = (tid & 7) * 4;
    int smB = tid >> 2, skB = (tid & 3) * 8;
    f32x4 acc[2] = {};
    for (int k0 = 0; k0 < K; k0 += 32) {
        uint2 va = make_uint2(0, 0);
        uint4 vx = make_uint4(0, 0, 0, 0);
        if (k0 + skA < K) va = *(const uint2*)(A + (size_t)(m0 + smA) * K + k0 + skA);
        if (n0 + smB < Ncols && k0 + skB < K) vx = *(const uint4*)(Bt + (size_t)(n0 + smB) * K + k0 + skB);
        __syncthreads();
        *(uint2*)&Alds[smA * TNC + skA] = va;
        *(uint4*)&Blds[smB * TNC + skB] = vx;
        __syncthreads();
        int arr = wr * 16 + (lane & 15), koff = (lane >> 4) * 8;
        int br = wc * 32 + (lane & 15);
        short8v a0 = *(const short8v*)&Alds[arr * TNC + koff];
        short8v b0 = *(const short8v*)&Blds[br * TNC + koff];
        short8v b1 = *(const short8v*)&Blds[(br + 16) * TNC + koff];
        acc[0] = __builtin_amdgcn_mfma_f32_16x16x32_bf16(a0, b0, acc[0], 0, 0, 0);
        acc[1] = __builtin_amdgcn_mfma_f32_16x16x32_bf16(a0, b1, acc[1], 0, 0, 0);
    }
    for (int ni = 0; ni < 2; ni++) {
        int col = n0 + wc * 32 + ni * 16 + (lane & 15);
        if (col >= Ncols) continue;
        int rbase = m0 + wr * 16 + (lane >> 4) * 4;
        for (int r = 0; r < 4; r++) {
            float v = acc[ni][r];
            if (mode == 0) v = v > 0.f ? v : (__expf(v) - 1.0f);
            else           v = 1.0f / (1.0f + __expf(-v));
            Out[(size_t)(rbase + r) * outStride + outColOff + col] = __float2bfloat16(v);
        }
    }
}

__global__ void k_gather(const bf16* full, const int* ids, void* out, const int* flags) {
    int idx = blockIdx.x * 256 + threadIdx.x;
    if (idx >= 64 * DD) return;
    int t = idx / DD, d = idx - t * DD;
    float v = __bfloat162float(full[(size_t)ids[t] * DD + d]);
    if (flags[0]) ((float*)out)[idx] = v;
    else ((bf16*)out)[idx] = __float2bfloat16(v);
}

extern "C" void kernel_launch(void* const* d_in, const int* in_sizes, int n_in,
                              void* d_out, int out_size, void* d_ws, size_t ws_size,
                              hipStream_t stream) {
    const void* emb = d_in[0];
    const void* Whd = d_in[1];
    const void* ahd = d_in[2];
    const void* wth = d_in[3];
    const void* Wo  = d_in[4];
    const void* ao  = d_in[5];
    const void* wto = d_in[6];
    const void* adj = d_in[7];
    const int* tid  = (const int*)d_in[8];

    char* p = (char*)d_ws;
    auto alloc = [&](size_t bytes) { void* r = (void*)p; p += ((bytes + 255) / 256) * 256; return r; };
    int*     flags   = (int*)    alloc(256);
    uint8_t* adjbits = (uint8_t*)alloc((size_t)NND * NB8);
    bf16*  X1t   = (bf16*) alloc((size_t)320 * NND * 2);     // emb^T, padded to 320 rows
    bf16*  X2t   = (bf16*) alloc((size_t)1280 * NND * 2);    // x2^T, padded to 1280 rows
    bf16*  x2    = (bf16*) alloc((size_t)NND * F2 * 2);
    bf16*  cc4   = (bf16*) alloc((size_t)HH * NND * 2 * DD * 2);
    bf16*  ccO   = (bf16*) alloc((size_t)NND * 2 * F2 * 2);
    bf16*  wtT4  = (bf16*) alloc((size_t)HH * DD * 2 * DD * 2);
    bf16*  wtTo  = (bf16*) alloc((size_t)DD * 2 * F2 * 2);
    bf16*  ofull = (bf16*) alloc((size_t)NND * DD * 2);
    float* uh1   = (float*)alloc((size_t)HH * DD * 4);
    float* uh2   = (float*)alloc((size_t)HH * DD * 4);
    float* uo1   = (float*)alloc((size_t)F2 * 4);
    float* uo2   = (float*)alloc((size_t)F2 * 4);
    float* Wh1h  = (float*)alloc((size_t)HH * NND * 4);
    float* Wh2h  = (float*)alloc((size_t)HH * NND * 4);
    float* Wh1o  = (float*)alloc((size_t)NND * 4);
    float* Wh2o  = (float*)alloc((size_t)NND * 4);

    dim3 tb(32, 8);
    k_detect<<<1, 64, 0, stream>>>(emb, adj, flags);
    k_adjpack<<<NND, NB8, 0, stream>>>(adj, flags, adjbits);
    hipMemsetAsync(X1t, 0, (size_t)320 * NND * 2, stream);
    hipMemsetAsync(X2t, 0, (size_t)1280 * NND * 2, stream);
    // X1t = emb^T: [R=3072][C=300] -> grid (10, 96)
    k_transpose<<<dim3((DD + 31) / 32, (NND + 31) / 32), tb, 0, stream>>>(emb, 0, X1t, NND, DD, flags, 1);
    k_uvec<<<dim3((DD + 3) / 4, HH), 256, 0, stream>>>(Whd, ahd, uh1, uh2, DD, DD,
                                                       (long)DD * DD, (long)2 * DD, DD, flags);
    k_gemv2<<<dim3(NND / 4, HH), 256, 0, stream>>>(emb, uh1, uh2, Wh1h, Wh2h, NND, DD, DD, NND, flags, 1);
    // heads fused attention GEMM (LDS-shared P, dup=1): grid (96, 1, 4)
    k_fatt3<<<dim3(96, 1, HH), 256, 0, stream>>>(Wh1h, Wh2h, NND, adjbits, X1t, cc4,
                                                 (long)NND * 2 * DD, 2 * DD, DD, 4 * PANEL);
    // wth block is [R=600][C=300] -> grid (10, 19)
    for (int l = 0; l < HH; l++)
        k_transpose<<<dim3((DD + 31) / 32, (2 * DD + 31) / 32), tb, 0, stream>>>(
            wth, (size_t)l * 2 * DD * DD, wtT4 + (size_t)l * DD * 2 * DD, 2 * DD, DD, flags, 1);
    // head-batched concat GEMM with ELU -> x2 column blocks: grid (5, 96, 4)
    k_ccgemm<<<dim3(5, 96, HH), 256, 0, stream>>>(cc4, wtT4, x2, 2 * DD, DD, F2, 0, 0,
                                                  (long)NND * 2 * DD, (long)DD * 2 * DD, DD);
    // output layer
    k_transpose<<<dim3((F2 + 31) / 32, (NND + 31) / 32), tb, 0, stream>>>(x2, 0, X2t, NND, F2, flags, 0);
    k_uvec<<<dim3((F2 + 3) / 4, 1), 256, 0, stream>>>(Wo, ao, uo1, uo2, F2, DD, 0, 0, 0, flags);
    k_gemv2<<<dim3(NND / 4, 1), 256, 0, stream>>>(x2, uo1, uo2, Wh1o, Wh2o, NND, F2, 0, 0, flags, 0);
    // output fused attention GEMM (dup=4): grid (96, 4, 1)
    k_fatt3<<<dim3(96, 4, 1), 256, 0, stream>>>(Wh1o, Wh2o, 0, adjbits, X2t, ccO,
                                                0, 2 * F2, F2, 4 * PANEL);
    // wto is [R=2400][C=300] -> grid (10, 75)
    k_transpose<<<dim3((DD + 31) / 32, (2 * F2 + 31) / 32), tb, 0, stream>>>(wto, 0, wtTo, 2 * F2, DD, flags, 1);
    k_ccgemm<<<dim3(5, 96, 1), 256, 0, stream>>>(ccO, wtTo, ofull, 2 * F2, DD, DD, 0, 1, 0, 0, 0);
    k_gather<<<(64 * DD + 255) / 256, 256, 0, stream>>>(ofull, tid, d_out, flags);
}